// Round 20
// baseline (26.412 us; speedup 1.0000x reference)
//
#include <hip/hip_runtime.h>

// PatchStd: out = sqrt( boxconv7(x^2) - boxconv7(x)^2 ), uniform 7x7 weight w.
// x: [16, 1, 1024, 1024] fp32, zero padding 3 on each side.
//
// R20 = R19 (26.37us: SH=32, block-cooperative LDS staging — 4 waves' size16
// DMAs tile the 1024-col row exactly, halo from neighbor segments, raw
// s_barrier after counted WAITV, NT stores, XCD-pair swizzle) with
// PAIR-ROW processing: stage + consume 2 rows per wait+barrier, halving the
// per-block sync count (38 -> 19). Slot = 2 rows; RING=4 pairs (8 rows,
// 33KB LDS, 2 blocks/CU). Depth rises to 6 rows incidentally (depth alone
// proven null R10/R17, so any delta attributes to the sync halving).
//
// Wait table (in-order vmcnt; per iter t: [wait][barrier][issue pair t+3 =
// 2 loads][consume row 2t (1 NT store if j>=6)][consume row 2t+1 (store)]):
//   N(t) = ops younger than pair t's last load (issued iter t-3):
//   = [t-3>=3: 2 stores] + sum_{i=t-2..t-1}(2*[i+3<=18] + 2*[i>=3])
//   -> t<=3:4 | 4:6 | 5:8 | 6..16:10 | 17:8 | 18:6.  Never 0 mid-loop.
// SLOTF=1032: 4-float guards both ends (edge b128 stays in-bounds, patched).

#define IMG_W 1024
#define IMG_H 1024
#define SH    32            // output rows per block strip
#define TPB   256
#define NP    19            // row-pairs per strip (38 input rows)
#define RING  4             // pair-slots
#define SLOTF 1032          // floats per row: 4 guard + 1024 + 4 guard

typedef float v4f __attribute__((ext_vector_type(4)));

#define WAITV(N) asm volatile("s_waitcnt vmcnt(" #N ")" ::: "memory")

__global__ __launch_bounds__(TPB) void patchstd_kernel(
    const float* __restrict__ img, const float* __restrict__ wptr,
    float* __restrict__ out)
{
    __shared__ float lds[RING * 2 * SLOTF];         // 33 KB

    const int tx   = threadIdx.x;
    const int w_   = tx >> 6;                       // wave id 0..3 (uniform)
    const int c0   = tx << 2;                       // first of 4 output cols

    // XCD-pair swizzle (R18): bid = b*256 + p*16 + z with y = 2p + b.
    const int bid = blockIdx.x;
    const int b   = bid >> 8;                       // 0..1
    const int p   = (bid >> 4) & 15;                // 0..15
    const int z   = bid & 15;                       // image index 0..15
    const int y0  = (2 * p + b) * SH;

    const float* base  = img + (size_t)z * (IMG_W * IMG_H);
    float*       obase = out + (size_t)z * (IMG_W * IMG_H);
    const float w = wptr[0];

    // Block-cooperative staging: lane src col = 4*tx (exact row tiling);
    // wave w_ writes row-slot floats [4+256w .. 4+256w+255].
    const float* gP = base + c0;

    // Issue BOTH rows of pair t into pair-slot t&3.
    auto issuePair = [&](int t) {
        #pragma unroll
        for (int r = 0; r < 2; ++r) {
            const int j  = 2 * t + r;
            const int rc = min(max(y0 - 3 + j, 0), IMG_H - 1);
            __builtin_amdgcn_global_load_lds(
                (const __attribute__((address_space(1))) void*)(gP + (size_t)rc * IMG_W),
                (__attribute__((address_space(3))) void*)
                    (&lds[((t & (RING - 1)) * 2 + r) * SLOTF + 4 + 256 * w_]), 16, 0, 0);
        }
    };

    // Horizontal 7-sums for 4 output cols from 12 raw values
    // (window for col c0+k = v[k+1..k+7]).
    auto hsum = [&](const float* v, float* h, float* q) {
        float s = v[1]+v[2]+v[3]+v[4]+v[5]+v[6]+v[7];
        h[0] = s;
        s = s - v[1] + v[8];  h[1] = s;
        s = s - v[2] + v[9];  h[2] = s;
        h[3] = s - v[3] + v[10];
        float sq[11];
        #pragma unroll
        for (int i = 1; i <= 10; ++i) sq[i] = v[i] * v[i];
        float t2 = sq[1]+sq[2]+sq[3]+sq[4]+sq[5]+sq[6]+sq[7];
        q[0] = t2;
        t2 = t2 - sq[1] + sq[8];  q[1] = t2;
        t2 = t2 - sq[2] + sq[9];  q[2] = t2;
        q[3] = t2 - sq[3] + sq[10];
    };

    float rh[7][4], rq[7][4];                       // h/q ring (7 rows)
    float vh[4] = {0.f,0.f,0.f,0.f};                // vertical running sums
    float vq[4] = {0.f,0.f,0.f,0.f};

    issuePair(0); issuePair(1); issuePair(2);       // 6 rows in flight

    // Full unroll: slots, vmcnt immediates, guards all compile-time.
    #pragma unroll
    for (int t = 0; t < NP; ++t) {
        if      (t <= 3)  WAITV(4);
        else if (t == 4)  WAITV(6);
        else if (t == 5)  WAITV(8);
        else if (t <= 16) WAITV(10);
        else if (t == 17) WAITV(8);
        else              WAITV(6);
        __builtin_amdgcn_s_barrier();
        asm volatile("" ::: "memory");              // no compiler reordering

        if (t + 3 < NP) issuePair(t + 3);           // overwrites pair-slot
                                                    // (t-1)&3: readers passed barrier

        #pragma unroll
        for (int r = 0; r < 2; ++r) {
            const int j = 2 * t + r;                // input row index (static)

            // Consume row j: slot floats c0..c0+11 = window cols c0-4..c0+7.
            const float* seg = &lds[((t & (RING - 1)) * 2 + r) * SLOTF + c0];
            const v4f* pq = (const v4f*)seg;
            v4f A = pq[0], B = pq[1], C = pq[2];
            float v[12] = {A.x,A.y,A.z,A.w, B.x,B.y,B.z,B.w, C.x,C.y,C.z,C.w};
            if (tx == 0)   { v[0]=0.f; v[1]=0.f; v[2]=0.f;  v[3]=0.f;  }
            if (tx == 255) { v[8]=0.f; v[9]=0.f; v[10]=0.f; v[11]=0.f; }

            float h[4], q[4];
            const int R = y0 - 3 + j;
            if (R < 0 || R >= IMG_H) {              // block-uniform branch
                #pragma unroll
                for (int k = 0; k < 4; ++k) { h[k] = 0.f; q[k] = 0.f; }
            } else {
                hsum(v, h, q);
            }

            if (j < 6) {                            // warm the vertical window
                #pragma unroll
                for (int k = 0; k < 4; ++k) {
                    rh[j][k] = h[k]; rq[j][k] = q[k];
                    vh[k] += h[k];   vq[k] += q[k];
                }
                if (j == 5) {
                    #pragma unroll
                    for (int k = 0; k < 4; ++k) { rh[6][k] = 0.f; rq[6][k] = 0.f; }
                }
            } else {                                // steady state: emit a row
                const int s = j % 7;                // departing row's slot
                float o[4];
                #pragma unroll
                for (int k = 0; k < 4; ++k) {
                    vh[k] += h[k] - rh[s][k];
                    vq[k] += q[k] - rq[s][k];
                    rh[s][k] = h[k]; rq[s][k] = q[k];
                    float mean = w * vh[k];
                    float var  = fmaf(w, vq[k], -(mean * mean));
                    o[k] = __builtin_amdgcn_sqrtf(fmaxf(var, 0.f));
                }
                v4f ov; ov.x = o[0]; ov.y = o[1]; ov.z = o[2]; ov.w = o[3];
                __builtin_nontemporal_store(
                    ov, reinterpret_cast<v4f*>(obase + (size_t)(y0 + j - 6) * IMG_W + c0));
            }
        }
    }
}

extern "C" void kernel_launch(void* const* d_in, const int* in_sizes, int n_in,
                              void* d_out, int out_size, void* d_ws, size_t ws_size,
                              hipStream_t stream) {
    const float* img = (const float*)d_in[0];
    const float* wt  = (const float*)d_in[1];
    float* out = (float*)d_out;
    (void)in_sizes; (void)n_in; (void)d_ws; (void)ws_size; (void)out_size;
    dim3 grid(512, 1, 1);                              // flat; decoded in-kernel
    patchstd_kernel<<<grid, dim3(TPB, 1, 1), 0, stream>>>(img, wt, out);
}

// Round 22
// 26.285 us; speedup vs baseline: 1.0048x; 1.0048x over previous
//
#include <hip/hip_runtime.h>

// PatchStd: out = sqrt( boxconv7(x^2) - boxconv7(x)^2 ), uniform 7x7 weight w.
// x: [16, 1, 1024, 1024] fp32, zero padding 3 on each side.
//
// R22 = exact revert to R19 (best passing kernel, 26.37us).
// R21's L3-bypass stores (nt sc0 sc1) were INCOHERENT with the harness's
// cached memset-zero lines (dirty zero lines evict over bypass-written HBM
// data) — mechanism dead, reverted.
// Structure: SH=32, 512 blocks=2/CU; block-cooperative LDS staging (4 waves'
// size16 global_load_lds DMAs tile the 1024-col row exactly, no clamp, no
// tail op); halo from neighbor waves' segments; raw s_barrier preceded by
// counted WAITV (never 0 mid-loop); 3x ds_read_b128 consume; sliding
// horizontal 7-sums; 7-deep h/q ring + vertical running sums; builtin NT
// stores; XCD-pair swizzle. SLOTF=1032: 4-float guards both ends.
// Wait table (1 load/row + 1 store/output; issue after barrier, wait before):
//   j<=6:2 | 7:3 | 8:4 | 9..35:5 | 36:4 | 37:3.

#define IMG_W 1024
#define IMG_H 1024
#define SH    32            // output rows per block strip
#define TPB   256
#define NR    (SH + 6)      // 38 input rows per strip
#define RING  4
#define SLOTF 1032          // 4 guard + 1024 data + 4 guard (floats)

typedef float v4f __attribute__((ext_vector_type(4)));

#define WAITV(N) asm volatile("s_waitcnt vmcnt(" #N ")" ::: "memory")

__global__ __launch_bounds__(TPB) void patchstd_kernel(
    const float* __restrict__ img, const float* __restrict__ wptr,
    float* __restrict__ out)
{
    __shared__ float lds[RING * SLOTF];             // 16.5 KB

    const int tx   = threadIdx.x;
    const int w_   = tx >> 6;                       // wave id 0..3 (uniform)
    const int c0   = tx << 2;                       // first of 4 output cols

    // XCD-pair swizzle (R18): bid = b*256 + p*16 + z with y = 2p + b.
    const int bid = blockIdx.x;
    const int b   = bid >> 8;                       // 0..1
    const int p   = (bid >> 4) & 15;                // 0..15
    const int z   = bid & 15;                       // image index 0..15
    const int y0  = (2 * p + b) * SH;

    const float* base  = img + (size_t)z * (IMG_W * IMG_H);
    float*       obase = out + (size_t)z * (IMG_W * IMG_H);
    const float w = wptr[0];

    // Block-cooperative staging: lane src col = 4*tx (exact row tiling, no
    // clamp); wave w_ writes slot floats [4+256w .. 4+256w+255].
    const float* gP = base + c0;

    auto issue = [&](int j) {
        const int rc = min(max(y0 - 3 + j, 0), IMG_H - 1);    // clamped row
        __builtin_amdgcn_global_load_lds(
            (const __attribute__((address_space(1))) void*)(gP + (size_t)rc * IMG_W),
            (__attribute__((address_space(3))) void*)
                (&lds[(j & (RING - 1)) * SLOTF + 4 + 256 * w_]), 16, 0, 0);
    };

    // Horizontal 7-sums for 4 output cols from 12 raw values
    // (window for col c0+k = v[k+1..k+7]).
    auto hsum = [&](const float* v, float* h, float* q) {
        float s = v[1]+v[2]+v[3]+v[4]+v[5]+v[6]+v[7];
        h[0] = s;
        s = s - v[1] + v[8];  h[1] = s;
        s = s - v[2] + v[9];  h[2] = s;
        h[3] = s - v[3] + v[10];
        float sq[11];
        #pragma unroll
        for (int i = 1; i <= 10; ++i) sq[i] = v[i] * v[i];
        float t = sq[1]+sq[2]+sq[3]+sq[4]+sq[5]+sq[6]+sq[7];
        q[0] = t;
        t = t - sq[1] + sq[8];  q[1] = t;
        t = t - sq[2] + sq[9];  q[2] = t;
        q[3] = t - sq[3] + sq[10];
    };

    float rh[7][4], rq[7][4];                       // h/q ring (7 rows)
    float vh[4] = {0.f,0.f,0.f,0.f};                // vertical running sums
    float vq[4] = {0.f,0.f,0.f,0.f};

    issue(0); issue(1); issue(2);                   // 3-deep pipeline fill

    // Full unroll: slots, vmcnt immediates, guards all compile-time.
    #pragma unroll
    for (int j = 0; j < NR; ++j) {
        // Own row-j DMA complete -> barrier -> all segments of row j visible.
        if      (j <= 6)  WAITV(2);
        else if (j == 7)  WAITV(3);
        else if (j == 8)  WAITV(4);
        else if (j <= 35) WAITV(5);
        else if (j == 36) WAITV(4);
        else              WAITV(3);
        __builtin_amdgcn_s_barrier();
        asm volatile("" ::: "memory");              // no compiler reordering

        if (j + 3 < NR) issue(j + 3);               // overwrites slot (j-1)&3:
                                                    // its readers passed this barrier

        // Consume row j: slot floats c0..c0+11 = window cols c0-4..c0+7.
        const float* seg = &lds[(j & (RING - 1)) * SLOTF + c0];
        const v4f* pq = (const v4f*)seg;
        v4f A = pq[0], B = pq[1], C = pq[2];
        float v[12] = {A.x,A.y,A.z,A.w, B.x,B.y,B.z,B.w, C.x,C.y,C.z,C.w};
        if (tx == 0)   { v[0]=0.f; v[1]=0.f; v[2]=0.f;  v[3]=0.f;  }
        if (tx == 255) { v[8]=0.f; v[9]=0.f; v[10]=0.f; v[11]=0.f; }

        float h[4], q[4];
        const int R = y0 - 3 + j;
        if (R < 0 || R >= IMG_H) {                  // block-uniform branch
            #pragma unroll
            for (int k = 0; k < 4; ++k) { h[k] = 0.f; q[k] = 0.f; }
        } else {
            hsum(v, h, q);
        }

        if (j < 6) {                                // warm the vertical window
            #pragma unroll
            for (int k = 0; k < 4; ++k) {
                rh[j][k] = h[k]; rq[j][k] = q[k];
                vh[k] += h[k];   vq[k] += q[k];
            }
            if (j == 5) {
                #pragma unroll
                for (int k = 0; k < 4; ++k) { rh[6][k] = 0.f; rq[6][k] = 0.f; }
            }
        } else {                                    // steady state: emit a row
            const int s = j % 7;                    // departing row's slot
            float o[4];
            #pragma unroll
            for (int k = 0; k < 4; ++k) {
                vh[k] += h[k] - rh[s][k];
                vq[k] += q[k] - rq[s][k];
                rh[s][k] = h[k]; rq[s][k] = q[k];
                float mean = w * vh[k];
                float var  = fmaf(w, vq[k], -(mean * mean));
                o[k] = __builtin_amdgcn_sqrtf(fmaxf(var, 0.f));
            }
            v4f ov; ov.x = o[0]; ov.y = o[1]; ov.z = o[2]; ov.w = o[3];
            __builtin_nontemporal_store(
                ov, reinterpret_cast<v4f*>(obase + (size_t)(y0 + j - 6) * IMG_W + c0));
        }
    }
}

extern "C" void kernel_launch(void* const* d_in, const int* in_sizes, int n_in,
                              void* d_out, int out_size, void* d_ws, size_t ws_size,
                              hipStream_t stream) {
    const float* img = (const float*)d_in[0];
    const float* wt  = (const float*)d_in[1];
    float* out = (float*)d_out;
    (void)in_sizes; (void)n_in; (void)d_ws; (void)ws_size; (void)out_size;
    dim3 grid(512, 1, 1);                              // flat; decoded in-kernel
    patchstd_kernel<<<grid, dim3(TPB, 1, 1), 0, stream>>>(img, wt, out);
}